// Round 1
// baseline (37.890 us; speedup 1.0000x reference)
//
#include <hip/hip_runtime.h>

// VirtualValueNetwork: out[b,i] = min_k max_j (bids[b,i]*exp(w[i,k,j]) + beta[i,k,j])
// B=16384, N=1024, K=2, J=3.
// R2: widen streams to 16 B/lane (float4 loads+stores, the gfx950 coalescing
// sweet spot -- fill kernel sustains 6.6 TB/s at dwordx4, we were at 5.36 TB/s
// with dwordx2). 4 buyers/thread, 4 rows/block, nontemporal on the pure
// streams, bids loads issued before param+exp work so exp hides under HBM.

typedef float f4 __attribute__((ext_vector_type(4)));

#define NB    1024
#define BATCH 16384
#define KK    2
#define JJ    3
#define ROWS  4            // rows per block; grid = 16384/4 = 4096 blocks

__global__ __launch_bounds__(256, 5) void vvn_kernel(
    const float* __restrict__ bids,
    const float* __restrict__ w,
    const float* __restrict__ beta,
    float* __restrict__ out)
{
    const int t  = threadIdx.x;        // 0..255
    const int i0 = t << 2;             // 4 consecutive buyers per thread
    const size_t base = (size_t)blockIdx.x * ROWS * NB + i0;

    // --- Issue the HBM stream loads FIRST (critical path): 4 x dwordx4 ---
    f4 bv[ROWS];
#pragma unroll
    for (int r = 0; r < ROWS; ++r) {
        bv[r] = __builtin_nontemporal_load(
            reinterpret_cast<const f4*>(&bids[base + (size_t)r * NB]));
    }

    // --- Params for 4 buyers: 24 consecutive floats each (96 B, 16B-aligned,
    // coalesced dwordx4; 48 KiB total across the grid -> L2-hot). Loaded and
    // exp'd while the bids loads are in flight. ---
    f4 wv[6], bb[6];
    {
        const f4* wp = reinterpret_cast<const f4*>(w    + (size_t)i0 * (KK * JJ));
        const f4* bp = reinterpret_cast<const f4*>(beta + (size_t)i0 * (KK * JJ));
#pragma unroll
        for (int q = 0; q < 6; ++q) { wv[q] = wp[q]; bb[q] = bp[q]; }
    }

    float ew[4][KK][JJ];
    float bt[4][KK][JJ];
#pragma unroll
    for (int u = 0; u < 4; ++u) {
#pragma unroll
        for (int k = 0; k < KK; ++k) {
#pragma unroll
            for (int j = 0; j < JJ; ++j) {
                const int idx = u * (KK * JJ) + k * JJ + j;  // compile-time after unroll
                ew[u][k][j] = __expf(reinterpret_cast<const float*>(wv)[idx]);
                bt[u][k][j] = reinterpret_cast<const float*>(bb)[idx];
            }
        }
    }

#pragma unroll
    for (int r = 0; r < ROWS; ++r) {
        f4 res;
#pragma unroll
        for (int u = 0; u < 4; ++u) {
            const float a = bv[r][u];
            float m0 = fmaf(a, ew[u][0][0], bt[u][0][0]);
            m0 = fmaxf(m0, fmaf(a, ew[u][0][1], bt[u][0][1]));
            m0 = fmaxf(m0, fmaf(a, ew[u][0][2], bt[u][0][2]));
            float m1 = fmaf(a, ew[u][1][0], bt[u][1][0]);
            m1 = fmaxf(m1, fmaf(a, ew[u][1][1], bt[u][1][1]));
            m1 = fmaxf(m1, fmaf(a, ew[u][1][2], bt[u][1][2]));
            res[u] = fminf(m0, m1);
        }
        __builtin_nontemporal_store(
            res, reinterpret_cast<f4*>(&out[base + (size_t)r * NB]));
    }
}

extern "C" void kernel_launch(void* const* d_in, const int* in_sizes, int n_in,
                              void* d_out, int out_size, void* d_ws, size_t ws_size,
                              hipStream_t stream) {
    const float* bids = (const float*)d_in[0];   // [16384, 1024]
    const float* w    = (const float*)d_in[1];   // [1024, 2, 3]
    const float* beta = (const float*)d_in[2];   // [1024, 2, 3]
    float* out = (float*)d_out;                  // [16384, 1024]

    vvn_kernel<<<dim3(BATCH / ROWS), dim3(256), 0, stream>>>(bids, w, beta, out);
}